// Round 5
// baseline (12.858 us; speedup 1.0000x reference)
//
#include <hip/hip_runtime.h>
#include <math.h>

// ---- problem constants ----
constexpr int   Hh    = 8;
constexpr float DC_S  = 0.01f;
constexpr int   DC_BW = 16;
constexpr float STOP_W = 8.0f;
constexpr int Bn = 16, Tn = 800, Sn = 160, NM = 80, Ln = 4;
constexpr int Kk = Tn / Sn;                 // 5
constexpr int MEL4 = Bn * Tn * NM / 4;      // 256000 float4 items
constexpr int DCI  = Ln * Bn * Hh * Sn;     // 81920 (l,bh,s) rows
constexpr int NITEMS = MEL4 + DCI;          // 337920
constexpr int BLK  = 256;
constexpr int GRID = NITEMS / BLK;          // 1320 blocks (exact)
// dc-first: blocks 0..319 = dc rows, 320..1319 = mel float4s (both exact)

// ws[blk] = float4{ mel_sum, dc_sum, stop_sum (blk0), sum_len (blk0) }
__global__ __launch_bounds__(BLK) void lossA(
    const int*   __restrict__ length,
    const float* __restrict__ stop_pred,
    const float* __restrict__ mels_pred,
    const float* __restrict__ mels_target,
    const float* __restrict__ align,
    float4*      __restrict__ ws)
{
    int i = blockIdx.x * BLK + threadIdx.x;
    float mel_acc = 0.f, dc_acc = 0.f;

    if (i < DCI) {
        // ---- diagonal-constraint banded gather: one (l,bh,s) row ----
        int s   = i % Sn;
        int lbh = i / Sn;                   // [L, B*H, S, T]
        int bh  = lbh % (Bn * Hh);
        int b   = bh % Bn;                  // head-major: bh = h*B + b
        float sm = (Tn >= length[b]) ? 1.f : 0.f;

        // band: t in [t_lo, t_hi), floor-division semantics
        int t_lo = (s < DC_BW) ? 0 : (s - DC_BW) / Kk + 1;
        int t_hi = (s + DC_BW) / Kk + 1;    // width <= 7, t_hi <= 36
        int base = t_lo & ~3;               // 16B-aligned window start
        const float4* r4 = reinterpret_cast<const float4*>(
            align + ((size_t)lbh * Sn + s) * (size_t)Tn + base);
        float4 va = r4[0], vb = r4[1], vc = r4[2];   // 12 elems cover window
        float v[12] = {va.x, va.y, va.z, va.w,
                       vb.x, vb.y, vb.z, vb.w,
                       vc.x, vc.y, vc.z, vc.w};
        float acc = 0.f;
        #pragma unroll
        for (int q = 0; q < 12; ++q) {
            int t = base + q;
            acc += (t >= t_lo && t < t_hi) ? v[q] : 0.f;
        }
        dc_acc = acc * sm;
    } else {
        // ---- masked L1 mel term, 4 elems per thread ----
        int im = i - DCI;                   // mel float4 index (coalesced)
        int bt = (im * 4) / NM;             // b*T + t
        int b  = bt / Tn;
        int t  = bt - b * Tn;
        float4 p = reinterpret_cast<const float4*>(mels_pred)[im];
        float4 g = reinterpret_cast<const float4*>(mels_target)[im];
        float  m = (t < length[b]) ? 1.f : 0.f;
        mel_acc = fabsf(p.x * m - g.x) + fabsf(p.y * m - g.y)
                + fabsf(p.z * m - g.z) + fabsf(p.w * m - g.w);
    }

    // block 0, wave 0, lanes<16: stop-BCE + sum_len (overlaps with dc work)
    float stop_t = 0.f, len_t = 0.f;
    if (blockIdx.x == 0 && threadIdx.x < Bn) {
        int len  = length[threadIdx.x];
        len_t    = (float)len;
        float p  = stop_pred[threadIdx.x * Tn + (len - 1)];
        float lg = logf(p);
        if (lg < -100.f) lg = -100.f;
        stop_t = -lg;                       // target = 1
    }

    // wave64 shuffle reduce -> LDS -> one float4 store per block (no atomics)
    for (int off = 32; off > 0; off >>= 1) {
        mel_acc += __shfl_down(mel_acc, off);
        dc_acc  += __shfl_down(dc_acc,  off);
        stop_t  += __shfl_down(stop_t, off);
        len_t   += __shfl_down(len_t, off);
    }
    __shared__ float smel[BLK / 64], sdc[BLK / 64], sst, sln;
    int wid = threadIdx.x >> 6;
    if ((threadIdx.x & 63) == 0) { smel[wid] = mel_acc; sdc[wid] = dc_acc; }
    if (threadIdx.x == 0)        { sst = stop_t; sln = len_t; }
    __syncthreads();
    if (threadIdx.x == 0) {
        ws[blockIdx.x] = make_float4(smel[0] + smel[1] + smel[2] + smel[3],
                                     sdc[0]  + sdc[1]  + sdc[2]  + sdc[3],
                                     sst, sln);   // sst/sln nonzero only blk 0
    }
}

// final: reduce 1320 float4 partials (L2-resident, 21 KB) + combine
__global__ __launch_bounds__(256) void lossB(
    const float4* __restrict__ ws,
    float*        __restrict__ out)
{
    float m = 0.f, d = 0.f, st = 0.f, ln = 0.f;
    for (int i = threadIdx.x; i < GRID; i += 256) {
        float4 p = ws[i];
        m  += p.x;
        d  += p.y;
        st += p.z;
        ln += p.w;
    }
    for (int off = 32; off > 0; off >>= 1) {
        m  += __shfl_down(m, off);
        d  += __shfl_down(d, off);
        st += __shfl_down(st, off);
        ln += __shfl_down(ln, off);
    }
    __shared__ float4 sp[4];
    int wid = threadIdx.x >> 6;
    if ((threadIdx.x & 63) == 0) sp[wid] = make_float4(m, d, st, ln);
    __syncthreads();
    if (threadIdx.x == 0) {
        float mel_sum = sp[0].x + sp[1].x + sp[2].x + sp[3].x;
        float dc_sum  = sp[0].y + sp[1].y + sp[2].y + sp[3].y;
        float stop_s  = sp[0].z + sp[1].z + sp[2].z + sp[3].z;
        float sum_len = sp[0].w + sp[1].w + sp[2].w + sp[3].w;
        float mel  = mel_sum / (float)(Bn * Tn * NM);
        float stop = STOP_W * stop_s / sum_len;
        float dc   = dc_sum / ((float)Hh * sum_len);
        out[0] = mel + stop - DC_S * dc;
    }
}

extern "C" void kernel_launch(void* const* d_in, const int* in_sizes, int n_in,
                              void* d_out, int out_size, void* d_ws, size_t ws_size,
                              hipStream_t stream)
{
    const int*   length      = (const int*)  d_in[0];
    // d_in[1] = mask (bool) — recomputed from length (prefix mask by construction)
    const float* stop_pred   = (const float*)d_in[2];
    const float* mels_pred   = (const float*)d_in[3];
    const float* mels_target = (const float*)d_in[4];
    const float* align       = (const float*)d_in[5];
    float*  out = (float*)d_out;
    float4* ws  = (float4*)d_ws;

    lossA<<<GRID, BLK, 0, stream>>>(length, stop_pred, mels_pred,
                                    mels_target, align, ws);
    lossB<<<1, 256, 0, stream>>>(ws, out);
}